// Round 8
// baseline (297.026 us; speedup 1.0000x reference)
//
#include <hip/hip_runtime.h>
#include <math.h>

#define HEADS 4
#define BATCH 8
#define SEQ   1024
#define CH    256
#define DH    64
#define RB    16          // q rows per block
#define NTHR  512         // 8 waves
#define SSTR  1032        // Sraw row stride in u16 (2064 B, 16B-mult)

typedef float  floatx4  __attribute__((ext_vector_type(4)));
typedef float  floatx2  __attribute__((ext_vector_type(2)));
typedef short  shortx8  __attribute__((ext_vector_type(8)));
typedef short  shortx4  __attribute__((ext_vector_type(4)));

__device__ __forceinline__ unsigned short f2bf(float f) {
    unsigned u = __float_as_uint(f);
    unsigned r = u + 0x7FFFu + ((u >> 16) & 1u);   // RNE; -inf stays -inf
    return (unsigned short)(r >> 16);
}
__device__ __forceinline__ float bf2f(unsigned short h) {
    return __uint_as_float(((unsigned)h) << 16);
}
__device__ __forceinline__ shortx8 pack8(float4 a, float4 b) {
    shortx8 r;
    r[0] = (short)f2bf(a.x); r[1] = (short)f2bf(a.y);
    r[2] = (short)f2bf(a.z); r[3] = (short)f2bf(a.w);
    r[4] = (short)f2bf(b.x); r[5] = (short)f2bf(b.y);
    r[6] = (short)f2bf(b.z); r[7] = (short)f2bf(b.w);
    return r;
}

// ---- prologue: one-time staging into workspace.
// qb/kb: bf16 [B,N,C].  vt: bf16 V transposed per head [b][h][d][n].
// pm: bit-packed mask for the SWAPPED-QK main kernel:
//     pm[((b*SEQ + row) << 5) + w*4 + qd], bit (mc*4+r) =
//     mask[b][row][mc*128 + w*16 + qd*4 + r].
__global__ __launch_bounds__(256)
void prep(const float* __restrict__ q, const float* __restrict__ k,
          const float* __restrict__ v, const void* __restrict__ maskp,
          unsigned short* __restrict__ qb, unsigned short* __restrict__ kb,
          unsigned short* __restrict__ vt, unsigned* __restrict__ pm)
{
    __shared__ unsigned short tl[64][68];
    const int t = threadIdx.x;
    const int bid = blockIdx.x;
    if (bid < 2048) {                       // q (0..1023) / k (1024..2047) convert
        const float* src = (bid < 1024) ? q : k;
        unsigned short* dst = (bid < 1024) ? qb : kb;
        size_t idx = (size_t)(bid & 1023) * 2048 + (size_t)t * 8;
        float4 a = *(const float4*)(src + idx);
        float4 b = *(const float4*)(src + idx + 4);
        *(shortx8*)(dst + idx) = pack8(a, b);
        return;
    }
    if (bid < 2560) {
        // V transpose-convert: block = (b, h, 64-row n-tile)
        const int vb = bid - 2048;
        const int nt = vb & 15, h = (vb >> 4) & 3, b = vb >> 6;
        const int n0 = nt * 64;
        const float* vsrc = v + ((size_t)(b * SEQ + n0)) * CH + h * DH;
        #pragma unroll
        for (int it = 0; it < 4; ++it) {
            int fid = it * 256 + t;
            int n = fid >> 4, cc = (fid & 15) * 4;
            float4 x = *(const float4*)(vsrc + (size_t)n * CH + cc);
            tl[n][cc]     = f2bf(x.x);
            tl[n][cc + 1] = f2bf(x.y);
            tl[n][cc + 2] = f2bf(x.z);
            tl[n][cc + 3] = f2bf(x.w);
        }
        __syncthreads();
        unsigned short* vout = vt + ((size_t)((b * HEADS + h) * DH)) * SEQ + n0;
        #pragma unroll
        for (int it = 0; it < 2; ++it) {
            int cid = it * 256 + t;
            int d = cid >> 3, nc = cid & 7;
            shortx8 r;
            #pragma unroll
            for (int j = 0; j < 8; ++j) r[j] = (short)tl[nc * 8 + j][d];
            *(shortx8*)(vout + (size_t)d * SEQ + nc * 8) = r;
        }
        return;
    }
    // ---- mask pack: block = (b, 8-row group); 256 thr = sub(8) x wq(32) ----
    const int vb2 = bid - 2560;              // 0..1023
    const int b = vb2 >> 7, rg = vb2 & 127;
    const int sub = t >> 5, wq = t & 31;     // wq = w*4+qd
    const int row = rg * 8 + sub;
    const int w_ = wq >> 2, qd_ = wq & 3;
    // dtype detect: int32 bool => misaligned high bytes all 0 in leading 4KB
    int fl;
    {
        const unsigned* mw = (const unsigned*)maskp;
        const int lane = t & 63;
        int found = 0;
        #pragma unroll
        for (int j = 0; j < 16; ++j)
            if (mw[lane * 16 + j] & 0xFFFFFF00u) found = 1;
        fl = (__ballot(found != 0) != 0ULL) ? 1 : 0;   // 1 => byte mask
    }
    const unsigned char* m8  = (const unsigned char*)maskp;
    const int*           m32 = (const int*)maskp;
    unsigned u = 0;
    #pragma unroll
    for (int mc = 0; mc < 8; ++mc) {
        #pragma unroll
        for (int r = 0; r < 4; ++r) {
            size_t idx = ((size_t)(b * SEQ + row)) * SEQ
                       + mc * 128 + w_ * 16 + qd_ * 4 + r;
            int mk = fl ? (int)m8[idx] : m32[idx];
            u |= (mk ? 1u : 0u) << (mc * 4 + r);
        }
    }
    pm[(((size_t)b * SEQ + row) << 5) + wq] = u;
}

// Swapped-QK^T structure (HK T12): compute mfma(Kfrag, Qfrag) so each lane
// holds a full 32-score slice of ONE q-row (=ln).  Softmax runs in
// registers (31 in-lane ops + shfl_xor 16/32 + tiny cross-wave LDS
// partials); dis becomes 8x float4 loads; pout is written as float4
// straight from f32 registers.  Sraw holds bf16 exp ONLY as the pass-3
// operand-transpose buffer (written once, read once).
__global__ __launch_bounds__(NTHR)
void attn_mfma(const unsigned short* __restrict__ qb,
               const unsigned short* __restrict__ kbf,
               const unsigned short* __restrict__ vt,
               const unsigned* __restrict__ pm,
               const float* __restrict__ dis, float* __restrict__ out,
               float* __restrict__ pout)
{
    __shared__ unsigned short Sraw[RB][SSTR];    // 33 KB: bf16 exp for pass 3
    __shared__ float Opart[RB][65];              // 4.2 KB partial O (pad 65)
    __shared__ float invs[RB];
    __shared__ float wmax[8][16];                // cross-wave row-stat partials
    __shared__ float wsum[8][16];

    const int t   = threadIdx.x;
    const int bid = blockIdx.x;
    const int b   = bid & (BATCH - 1);     // XCD-pinned batch
    const int h   = (bid >> 3) & (HEADS - 1);
    const int n0  = (bid >> 5) * RB;

    const int lane = t & 63;
    const int w    = t >> 6;       // wave 0..7
    const int ln   = lane & 15;    // q-row owned by this lane
    const int qd   = lane >> 4;    // quad: k-slice / score-col subgroup

    // packed mask: one u32 = this lane's 32 scores (row ln)
    const unsigned mb = pm[(((size_t)b * SEQ + n0 + ln) << 5) + w * 4 + qd];

    // ---- Q B-frags (same loads as before; now the B operand) ----
    const unsigned short* qrow = qb + ((size_t)(b * SEQ + n0 + ln)) * CH + h * DH;
    shortx8 aq0 = *(const shortx8*)(qrow + qd * 8);
    shortx8 aq1 = *(const shortx8*)(qrow + 32 + qd * 8);

    const unsigned short* kbase = kbf + ((size_t)(b * SEQ)) * CH + h * DH;
    const unsigned short* vbase = vt + ((size_t)((b * HEADS + h) * DH)) * SEQ;
    const float* disrow =
        dis + ((size_t)(b * SEQ + n0 + ln)) * SEQ + w * 16 + qd * 4;

    // ---- Pass 1: S^T tiles; lane accumulates row ln, cols mc*128+w*16+qd*4+r
    float s[32];
    #pragma unroll
    for (int mc = 0; mc < 8; ++mc) {
        const int mgb = mc * 128 + w * 16;                  // score-col base
        const unsigned short* krow = kbase + (size_t)(mgb + ln) * CH;
        shortx8 kf0 = *(const shortx8*)(krow + qd * 8);
        shortx8 kf1 = *(const shortx8*)(krow + 32 + qd * 8);
        float4 dv = *(const float4*)(disrow + mc * 128);    // 4 consecutive cols
        floatx4 acc = {0.f, 0.f, 0.f, 0.f};
        acc = __builtin_amdgcn_mfma_f32_16x16x32_bf16(kf0, aq0, acc, 0, 0, 0);
        acc = __builtin_amdgcn_mfma_f32_16x16x32_bf16(kf1, aq1, acc, 0, 0, 0);
        s[mc*4+0] = ((mb >> (mc*4+0)) & 1u) ? -INFINITY : (acc[0] + dv.x) * 0.125f;
        s[mc*4+1] = ((mb >> (mc*4+1)) & 1u) ? -INFINITY : (acc[1] + dv.y) * 0.125f;
        s[mc*4+2] = ((mb >> (mc*4+2)) & 1u) ? -INFINITY : (acc[2] + dv.z) * 0.125f;
        s[mc*4+3] = ((mb >> (mc*4+3)) & 1u) ? -INFINITY : (acc[3] + dv.w) * 0.125f;
    }

    // ---- in-register softmax: row = ln ----
    float mx = s[0];
    #pragma unroll
    for (int i = 1; i < 32; ++i) mx = fmaxf(mx, s[i]);
    mx = fmaxf(mx, __shfl_xor(mx, 16));     // reduce across qd groups
    mx = fmaxf(mx, __shfl_xor(mx, 32));
    if (qd == 0) wmax[w][ln] = mx;
    __syncthreads();                         // B1
    #pragma unroll
    for (int j = 0; j < 8; ++j) mx = fmaxf(mx, wmax[j][ln]);   // broadcast reads

    float sum = 0.f;
    #pragma unroll
    for (int i = 0; i < 32; ++i) {
        float x = __expf(s[i] - mx);         // exp(-inf)=0
        s[i] = x;
        sum += x;
    }
    sum += __shfl_xor(sum, 16);
    sum += __shfl_xor(sum, 32);
    if (qd == 0) wsum[w][ln] = sum;
    __syncthreads();                         // B2
    float tot = 0.f;
    #pragma unroll
    for (int j = 0; j < 8; ++j) tot += wsum[j][ln];
    const float inv = 1.0f / tot;
    if (w == 0 && qd == 0) invs[ln] = inv;

    // ---- write bf16 exp to Sraw (pass-3 operand) + normalized p_attn
    // (float4 straight from registers, zero conversions) ----
    float* prow = pout + ((size_t)((h * BATCH + b) * SEQ + n0 + ln)) * SEQ
                + w * 16 + qd * 4;
    #pragma unroll
    for (int mc = 0; mc < 8; ++mc) {
        shortx4 ev;
        ev[0] = (short)f2bf(s[mc*4+0]);
        ev[1] = (short)f2bf(s[mc*4+1]);
        ev[2] = (short)f2bf(s[mc*4+2]);
        ev[3] = (short)f2bf(s[mc*4+3]);
        *(shortx4*)&Sraw[ln][mc * 128 + w * 16 + qd * 4] = ev;
        float4 pv = { s[mc*4+0] * inv, s[mc*4+1] * inv,
                      s[mc*4+2] * inv, s[mc*4+3] * inv };
        *(float4*)(prow + mc * 128) = pv;
    }
    __syncthreads();                         // B3: Sraw + invs visible

    // ---- Pass 3: O = (E V). m-range split across wave halves; dual acc ----
    const int hm = w >> 2;            // m-half 0/1
    const int c  = (w & 3) * 16;      // output col slice
    floatx4 accA = {0.f, 0.f, 0.f, 0.f};
    floatx4 accB = {0.f, 0.f, 0.f, 0.f};
    const unsigned short* vcol = vbase + (size_t)(c + ln) * SEQ;
    #pragma unroll 4
    for (int it = 0; it < 16; it += 2) {
        const int kk0 = hm * 512 + (it >> 1) * 64 + qd * 8;
        const int kk1 = kk0 + 32;
        shortx8 af0  = *(const shortx8*)&Sraw[ln][kk0];
        shortx8 bf0  = *(const shortx8*)(vcol + kk0);
        shortx8 af1  = *(const shortx8*)&Sraw[ln][kk1];
        shortx8 bf1  = *(const shortx8*)(vcol + kk1);
        accA = __builtin_amdgcn_mfma_f32_16x16x32_bf16(af0, bf0, accA, 0, 0, 0);
        accB = __builtin_amdgcn_mfma_f32_16x16x32_bf16(af1, bf1, accB, 0, 0, 0);
    }
    floatx4 acco;
    acco[0] = accA[0] + accB[0];
    acco[1] = accA[1] + accB[1];
    acco[2] = accA[2] + accB[2];
    acco[3] = accA[3] + accB[3];

    if (hm == 1) {
        #pragma unroll
        for (int r = 0; r < 4; ++r) Opart[qd * 4 + r][c + ln] = acco[r];
    }
    __syncthreads();                         // B4
    if (hm == 0) {
        #pragma unroll
        for (int r = 0; r < 4; ++r) {
            int row = qd * 4 + r;
            float ov = (acco[r] + Opart[row][c + ln]) * invs[row];
            out[((size_t)(b * SEQ + n0 + row)) * CH + h * DH + c + ln] = ov;
        }
    }
}

extern "C" void kernel_launch(void* const* d_in, const int* in_sizes, int n_in,
                              void* d_out, int out_size, void* d_ws, size_t ws_size,
                              hipStream_t stream) {
    const float* q    = (const float*)d_in[0];
    const float* k    = (const float*)d_in[1];
    const float* v    = (const float*)d_in[2];
    const void*  mask = d_in[3];
    const float* dis  = (const float*)d_in[4];
    float* out  = (float*)d_out;
    float* pout = out + (size_t)BATCH * SEQ * CH;   // p_attn after out

    // workspace: qb | kb | vt (each 2M bf16 = 4 MB) | pm (1 MB) => 13 MB
    unsigned short* qb  = (unsigned short*)d_ws;
    unsigned short* kbw = qb  + (size_t)BATCH * SEQ * CH;
    unsigned short* vtw = kbw + (size_t)BATCH * SEQ * CH;
    unsigned*       pmw = (unsigned*)(vtw + (size_t)BATCH * SEQ * CH);
    (void)ws_size;

    prep<<<3584, 256, 0, stream>>>(q, k, v, mask, qb, kbw, vtw, pmw);
    attn_mfma<<<HEADS * BATCH * (SEQ / RB), NTHR, 0, stream>>>(
        qb, kbw, vtw, pmw, dis, out, pout);
}